// Round 4
// baseline (668.796 us; speedup 1.0000x reference)
//
#include <hip/hip_runtime.h>

// Problem constants
#define HDIM 1024
#define IDIM 2816
#define NEXP 8
#define NTOK 4096      // B*S
#define NROWS 8192     // NTOK * K(=2)
#define RPAD 8320      // NROWS + 128 pad rows (tile overrun)
#define MAXT 71        // max total 128-row tiles
#define GU_NYT 44      // 2*IDIM/128
#define DN_NYT 8       // HDIM/128
#define GU_TG 8        // gateup supertile: t-group size
#define GU_NTG 9       // ceil(MAXT/GU_TG)
#define GU_NWG (GU_NTG * GU_NYT * GU_TG)   // 3168 = 8*396
#define DN_NWG (MAXT * DN_NYT)             // 568 = 8*71

typedef short bf16x8 __attribute__((ext_vector_type(8)));
typedef float f32x4 __attribute__((ext_vector_type(4)));

static __device__ __forceinline__ unsigned short f2bf(float f) {
    union { float f; unsigned int i; } v; v.f = f;
    return (unsigned short)((v.i + 0x7fffu + ((v.i >> 16) & 1u)) >> 16);  // RNE
}

// async global->LDS, 16B/lane; LDS dest = wave-uniform base + lane*16
static __device__ __forceinline__ void gload16(const void* g, void* l) {
    __builtin_amdgcn_global_load_lds(
        (const __attribute__((address_space(1))) unsigned int*)g,
        (__attribute__((address_space(3))) unsigned int*)l, 16, 0, 0);
}

// ---------------------------------------------------------------------------
// 1) Gating: one wave per token, fp64 accumulate for stable top-2 ordering.
// ---------------------------------------------------------------------------
__global__ __launch_bounds__(256) void gating_kernel(
    const float* __restrict__ x, const float* __restrict__ Wgate,
    const float* __restrict__ bgate, float* __restrict__ logits_out,
    int* __restrict__ counts, int* __restrict__ topi, float* __restrict__ topv)
{
    int wave = (blockIdx.x << 2) + (threadIdx.x >> 6);
    int lane = threadIdx.x & 63;
    if (wave >= NTOK) return;
    const float* xr = x + (size_t)wave * HDIM;

    double acc[NEXP];
#pragma unroll
    for (int e = 0; e < NEXP; ++e) acc[e] = 0.0;

    for (int it = 0; it < HDIM / 64; ++it) {
        int h = lane + (it << 6);
        float xv = xr[h];
        const float* wr = Wgate + (size_t)h * NEXP;
#pragma unroll
        for (int e = 0; e < NEXP; ++e) acc[e] += (double)xv * (double)wr[e];
    }
#pragma unroll
    for (int e = 0; e < NEXP; ++e) {
        double v = acc[e];
        for (int off = 32; off; off >>= 1) v += __shfl_xor(v, off, 64);
        acc[e] = v + (double)bgate[e];
    }
    float lf[NEXP];
#pragma unroll
    for (int e = 0; e < NEXP; ++e) lf[e] = (float)acc[e];

    if (lane < NEXP) logits_out[(size_t)wave * NEXP + lane] = lf[lane];

    if (lane == 0) {
        int i1 = 0; float v1 = lf[0];
#pragma unroll
        for (int e = 1; e < NEXP; ++e) if (lf[e] > v1) { v1 = lf[e]; i1 = e; }
        int i2 = -1; float v2 = -3.0e38f;
#pragma unroll
        for (int e = 0; e < NEXP; ++e) {
            if (e == i1) continue;
            if (lf[e] > v2) { v2 = lf[e]; i2 = e; }
        }
        topi[wave * 2 + 0] = i1; topv[wave * 2 + 0] = v1;
        topi[wave * 2 + 1] = i2; topv[wave * 2 + 1] = v2;
        atomicAdd(&counts[i1], 1);
        atomicAdd(&counts[i2], 1);
    }
}

// ---------------------------------------------------------------------------
// 2) Offsets + device-built tile table (e, m0) per 128-row tile
// ---------------------------------------------------------------------------
__global__ void offsets_kernel(const int* __restrict__ counts,
                               int* __restrict__ offs, int* __restrict__ cursor,
                               int* __restrict__ ntile, int* __restrict__ te,
                               int* __restrict__ tm0)
{
    if (threadIdx.x == 0 && blockIdx.x == 0) {
        int s = 0;
        for (int e = 0; e < NEXP; ++e) { offs[e] = s; cursor[e] = s; s += counts[e]; }
        offs[NEXP] = s;
        int nt = 0;
        for (int e = 0; e < NEXP; ++e) {
            int c = counts[e], base = offs[e];
            for (int mt = 0; mt * 128 < c; ++mt) { te[nt] = e; tm0[nt] = base + mt * 128; ++nt; }
        }
        *ntile = nt;
    }
}

// ---------------------------------------------------------------------------
// 3) Scatter: pack selected token rows as bf16 into Xg[pos]; record weight+token
// ---------------------------------------------------------------------------
__global__ __launch_bounds__(256) void scatter_kernel(
    const float* __restrict__ x, const int* __restrict__ topi,
    const float* __restrict__ topv, int* __restrict__ cursor,
    float* __restrict__ row_w, int* __restrict__ tok_of,
    unsigned short* __restrict__ Xg)
{
    int p = (blockIdx.x << 2) + (threadIdx.x >> 6);
    int lane = threadIdx.x & 63;
    if (p >= NROWS) return;
    int n = p >> 1;
    int e = topi[p];
    float w = topv[p];
    int pos = 0;
    if (lane == 0) {
        pos = atomicAdd(&cursor[e], 1);
        row_w[pos] = w;
        tok_of[pos] = n;
    }
    pos = __shfl(pos, 0, 64);
    const float* xr = x + (size_t)n * HDIM;
    unsigned short* dst = Xg + (size_t)pos * HDIM;
#pragma unroll
    for (int it = 0; it < HDIM / 256; ++it) {
        int idx = (it * 64 + lane) * 4;
        float4 v = *reinterpret_cast<const float4*>(&xr[idx]);
        ushort4 o;
        o.x = f2bf(v.x); o.y = f2bf(v.y); o.z = f2bf(v.z); o.w = f2bf(v.w);
        *reinterpret_cast<ushort4*>(&dst[idx]) = o;
    }
}

// ---------------------------------------------------------------------------
// 4) Fused gate+up GEMM, B from NATIVE fp32 Wg/Wu (no pre-transpose):
//    128x128 tile, BK=64, 4 waves. A: bf16 via global_load_lds with
//    XOR-pre-swizzled source (T2, both-sides rule). B: coalesced k-strided
//    fp32 loads -> bf16 pack -> ds_write_b64 into swizzled transposed layout.
//    Virtual N = interleaved 16 gate / 16 up columns (same-lane silu fuse).
//    L2 supertile: t-groups of GU_TG, ny inner; bijective XCD chunking.
// ---------------------------------------------------------------------------
__global__ __launch_bounds__(256, 4) void gateup_kernel(
    const unsigned short* __restrict__ Xg,
    const float* __restrict__ Wg, const float* __restrict__ Wu,
    const int* __restrict__ offs,
    const int* __restrict__ ntile, const int* __restrict__ te,
    const int* __restrict__ tm0, unsigned short* __restrict__ hbuf)
{
    __shared__ unsigned short As[128 * 64];
    __shared__ unsigned short Bs[128 * 64];

    // XCD chunking (3168 = 8*396) then supertile decode: tg-block of 352 wgs,
    // inside: ny outer (44), ti inner (8) -> 8 A-panels + 1 B-panel in L2.
    int bid = blockIdx.x;
    int xcd = bid & 7, rest = bid >> 3;
    int wg = xcd * (GU_NWG / 8) + rest;
    int tg = wg / (GU_NYT * GU_TG);
    int r2 = wg % (GU_NYT * GU_TG);
    int ny = r2 >> 3, ti = r2 & 7;
    int t = tg * GU_TG + ti;
    if (t >= *ntile) return;

    const int e = te[t];
    const int m0 = tm0[t];
    const int r1 = offs[e + 1];
    const int n0i = ny * 64;                 // i-range base (64 wide, g+u)

    const float* wgp = Wg + (size_t)e * HDIM * IDIM;
    const float* wup = Wu + (size_t)e * HDIM * IDIM;

    const int tid = threadIdx.x;
    const int lane = tid & 63, wv = tid >> 6;
    const int wr = (wv >> 1) * 64, wc = (wv & 1) * 64;
    const int lr = lane & 15, kq16 = lane >> 4;     // c16 sub-index 0..3

    // A staging: thread -> (row = ch*32 + tid>>3, chunk c16 = tid&7)
    const int a_row8 = tid >> 3;
    const int a_c16 = tid & 7;
    // B staging: thread -> n = tid&127, kq = u*2 + (tid>>7)
    const int bn = tid & 127;
    const int bsrc = (bn >> 4) & 1;
    const int biloc = ((bn >> 5) << 4) | (bn & 15);
    const float* bbase = (bsrc ? wup : wgp) + n0i + biloc;
    const int kq_hi = tid >> 7;
    const int bswz_row = bn * 64;            // shorts base of row bn

    f32x4 zero = {0.f, 0.f, 0.f, 0.f};
    f32x4 acc[4][4];
#pragma unroll
    for (int m = 0; m < 4; ++m)
#pragma unroll
        for (int n = 0; n < 4; ++n) acc[m][n] = zero;

    for (int k0 = 0; k0 < HDIM; k0 += 64) {
        __syncthreads();
        // ---- stage B: 8 units of (4 k-strided fp32 loads -> 1 ds_write_b64)
        unsigned int bpack[8][2];
#pragma unroll
        for (int u = 0; u < 8; ++u) {
            int kq = u * 2 + kq_hi;                        // 0..15
            const float* sp = bbase + (size_t)(k0 + kq * 4) * IDIM;
            float v0 = sp[0];
            float v1 = sp[IDIM];
            float v2 = sp[2 * IDIM];
            float v3 = sp[3 * IDIM];
            bpack[u][0] = (unsigned)f2bf(v0) | ((unsigned)f2bf(v1) << 16);
            bpack[u][1] = (unsigned)f2bf(v2) | ((unsigned)f2bf(v3) << 16);
        }
        // ---- stage A: 4 swizzled-source gload16
#pragma unroll
        for (int ch = 0; ch < 4; ++ch) {
            int row = ch * 32 + a_row8;
            int c16s = a_c16 ^ (row & 7);                  // inverse swizzle on source
            gload16(&Xg[(size_t)(m0 + row) * HDIM + k0 + c16s * 8],
                    &As[ch * 2048 + tid * 8]);
        }
        // ---- B writes (after loads complete)
#pragma unroll
        for (int u = 0; u < 8; ++u) {
            int kq = u * 2 + kq_hi;
            int soff = bswz_row + (((kq >> 1) ^ (bn & 7)) << 3) + ((kq & 1) << 2); // shorts
            *reinterpret_cast<uint2*>(&Bs[soff]) = *reinterpret_cast<uint2*>(bpack[u]);
        }
        __syncthreads();

#pragma unroll
        for (int ks = 0; ks < 2; ++ks) {
            bf16x8 af[4], bf[4];
#pragma unroll
            for (int m = 0; m < 4; ++m) {
                int row = wr + m * 16 + lr;
                int sw = (ks * 4 + kq16) ^ (row & 7);
                af[m] = *reinterpret_cast<const bf16x8*>(&As[row * 64 + sw * 8]);
            }
#pragma unroll
            for (int n = 0; n < 4; ++n) {
                int row = wc + n * 16 + lr;
                int sw = (ks * 4 + kq16) ^ (row & 7);
                bf[n] = *reinterpret_cast<const bf16x8*>(&Bs[row * 64 + sw * 8]);
            }
#pragma unroll
            for (int m = 0; m < 4; ++m)
#pragma unroll
                for (int n = 0; n < 4; ++n)
                    acc[m][n] = __builtin_amdgcn_mfma_f32_16x16x32_bf16(af[m], bf[n], acc[m][n], 0, 0, 0);
        }
    }

    // epilogue: frag parity n even = gate, n odd = up (same lane, same i)
    const int rr = (lane >> 4) * 4;
    const int iloc0 = ((wc >> 5) << 4) + lr;
    const int col0 = ny * 64 + iloc0;
#pragma unroll
    for (int m = 0; m < 4; ++m) {
#pragma unroll
        for (int j = 0; j < 4; ++j) {
            int grow = m0 + wr + m * 16 + rr + j;
            if (grow < r1) {
                unsigned short* hr = &hbuf[(size_t)grow * IDIM + col0];
                float g0 = acc[m][0][j], u0 = acc[m][1][j];
                float g1 = acc[m][2][j], u1 = acc[m][3][j];
                hr[0]  = f2bf(g0 / (1.0f + __expf(-g0)) * u0);
                hr[16] = f2bf(g1 / (1.0f + __expf(-g1)) * u1);
            }
        }
    }
}

// ---------------------------------------------------------------------------
// 5) Down GEMM + fused combine; B from NATIVE fp32 Wd [e][I][H].
//    Per-XCD ny slice (wg = xcd*71 + rest): Wd column slice resident in L2,
//    hbuf A-panels stream (L3-resident).
// ---------------------------------------------------------------------------
__global__ __launch_bounds__(256, 4) void down_kernel(
    const unsigned short* __restrict__ hbuf,
    const float* __restrict__ Wd,
    const int* __restrict__ offs,
    const int* __restrict__ ntile, const int* __restrict__ te,
    const int* __restrict__ tm0,
    const float* __restrict__ row_w, const int* __restrict__ tok_of,
    float* __restrict__ out)
{
    __shared__ unsigned short As[128 * 64];
    __shared__ unsigned short Bs[128 * 64];

    int bid = blockIdx.x;                          // 568 = 8*71
    int xcd = bid & 7, rest = bid >> 3;
    int wg = xcd * (DN_NWG / 8) + rest;
    int t = wg % MAXT;
    int ny = wg / MAXT;
    if (t >= *ntile) return;

    const int e = te[t];
    const int m0 = tm0[t];
    const int r1 = offs[e + 1];
    const int n0 = ny * 128;

    const float* wd = Wd + (size_t)e * IDIM * HDIM;

    const int tid = threadIdx.x;
    const int lane = tid & 63, wv = tid >> 6;
    const int wr = (wv >> 1) * 64, wc = (wv & 1) * 64;
    const int lr = lane & 15, kq16 = lane >> 4;

    const int a_row8 = tid >> 3;
    const int a_c16 = tid & 7;
    const int bn = tid & 127;
    const float* bbase = wd + n0 + bn;
    const int kq_hi = tid >> 7;
    const int bswz_row = bn * 64;

    f32x4 zero = {0.f, 0.f, 0.f, 0.f};
    f32x4 acc[4][4];
#pragma unroll
    for (int m = 0; m < 4; ++m)
#pragma unroll
        for (int n = 0; n < 4; ++n) acc[m][n] = zero;

    for (int k0 = 0; k0 < IDIM; k0 += 64) {
        __syncthreads();
        unsigned int bpack[8][2];
#pragma unroll
        for (int u = 0; u < 8; ++u) {
            int kq = u * 2 + kq_hi;
            const float* sp = bbase + (size_t)(k0 + kq * 4) * HDIM;
            float v0 = sp[0];
            float v1 = sp[HDIM];
            float v2 = sp[2 * HDIM];
            float v3 = sp[3 * HDIM];
            bpack[u][0] = (unsigned)f2bf(v0) | ((unsigned)f2bf(v1) << 16);
            bpack[u][1] = (unsigned)f2bf(v2) | ((unsigned)f2bf(v3) << 16);
        }
#pragma unroll
        for (int ch = 0; ch < 4; ++ch) {
            int row = ch * 32 + a_row8;
            int c16s = a_c16 ^ (row & 7);
            gload16(&hbuf[(size_t)(m0 + row) * IDIM + k0 + c16s * 8],
                    &As[ch * 2048 + tid * 8]);
        }
#pragma unroll
        for (int u = 0; u < 8; ++u) {
            int kq = u * 2 + kq_hi;
            int soff = bswz_row + (((kq >> 1) ^ (bn & 7)) << 3) + ((kq & 1) << 2);
            *reinterpret_cast<uint2*>(&Bs[soff]) = *reinterpret_cast<uint2*>(bpack[u]);
        }
        __syncthreads();

#pragma unroll
        for (int ks = 0; ks < 2; ++ks) {
            bf16x8 af[4], bf[4];
#pragma unroll
            for (int m = 0; m < 4; ++m) {
                int row = wr + m * 16 + lr;
                int sw = (ks * 4 + kq16) ^ (row & 7);
                af[m] = *reinterpret_cast<const bf16x8*>(&As[row * 64 + sw * 8]);
            }
#pragma unroll
            for (int n = 0; n < 4; ++n) {
                int row = wc + n * 16 + lr;
                int sw = (ks * 4 + kq16) ^ (row & 7);
                bf[n] = *reinterpret_cast<const bf16x8*>(&Bs[row * 64 + sw * 8]);
            }
#pragma unroll
            for (int m = 0; m < 4; ++m)
#pragma unroll
                for (int n = 0; n < 4; ++n)
                    acc[m][n] = __builtin_amdgcn_mfma_f32_16x16x32_bf16(af[m], bf[n], acc[m][n], 0, 0, 0);
        }
    }

    const int rr = (lane >> 4) * 4;
#pragma unroll
    for (int m = 0; m < 4; ++m) {
#pragma unroll
        for (int j = 0; j < 4; ++j) {
            int grow = m0 + wr + m * 16 + rr + j;
            if (grow < r1) {
                float w = row_w[grow];
                int tok = tok_of[grow];
                float* orow = out + (size_t)tok * HDIM + n0 + wc + lr;
#pragma unroll
                for (int n = 0; n < 4; ++n)
                    atomicAdd(&orow[n * 16], acc[m][n][j] * w);
            }
        }
    }
}

// ---------------------------------------------------------------------------
// ws layout (bytes):
//   [0,          17,039,360)   Xg bf16 [RPAD][HDIM]
//   [17,039,360, 63,897,600)   hbuf bf16 [RPAD][IDIM]
//   [63,897,600, ...)          meta
// ---------------------------------------------------------------------------
extern "C" void kernel_launch(void* const* d_in, const int* in_sizes, int n_in,
                              void* d_out, int out_size, void* d_ws, size_t ws_size,
                              hipStream_t stream)
{
    const float* x     = (const float*)d_in[0];
    const float* Wgate = (const float*)d_in[1];
    const float* bgate = (const float*)d_in[2];
    const float* Wg    = (const float*)d_in[3];
    const float* Wu    = (const float*)d_in[4];
    const float* Wd    = (const float*)d_in[5];
    float* out = (float*)d_out;
    float* logits = out + (size_t)NTOK * HDIM;

    char* ws = (char*)d_ws;
    unsigned short* Xg   = (unsigned short*)ws;
    unsigned short* hbuf = (unsigned short*)(ws + 17039360);
    char* meta = ws + 63897600;
    int*   counts = (int*)(meta);
    int*   offs   = (int*)(meta + 64);
    int*   cursor = (int*)(meta + 128);
    int*   ntile  = (int*)(meta + 192);
    int*   te     = (int*)(meta + 256);     // 128 ints
    int*   tm0    = (int*)(meta + 768);     // 128 ints
    int*   topi   = (int*)(meta + 2048);    // NROWS ints
    float* topv   = (float*)(meta + 34816);
    float* row_w  = (float*)(meta + 67584);
    int*   tok_of = (int*)(meta + 100352);

    hipMemsetAsync(counts, 0, 32, stream);
    hipMemsetAsync(out, 0, (size_t)NTOK * HDIM * sizeof(float), stream);

    gating_kernel<<<NTOK / 4, 256, 0, stream>>>(x, Wgate, bgate, logits, counts, topi, topv);
    offsets_kernel<<<1, 64, 0, stream>>>(counts, offs, cursor, ntile, te, tm0);
    scatter_kernel<<<NROWS / 4, 256, 0, stream>>>(x, topi, topv, cursor, row_w, tok_of, Xg);

    gateup_kernel<<<GU_NWG, 256, 0, stream>>>(Xg, Wg, Wu, offs, ntile, te, tm0, hbuf);
    down_kernel<<<DN_NWG, 256, 0, stream>>>(hbuf, Wd, offs, ntile, te, tm0, row_w, tok_of, out);
}

// Round 5
// 483.276 us; speedup vs baseline: 1.3839x; 1.3839x over previous
//
#include <hip/hip_runtime.h>

// Problem constants
#define HDIM 1024
#define IDIM 2816
#define NEXP 8
#define NTOK 4096      // B*S
#define NROWS 8192     // NTOK * K(=2)
#define RPAD 8320      // NROWS + 128 pad rows (tile overrun)
#define MAXT 71        // max total 128-row tiles
#define GU_NYT 44      // 2*IDIM/128
#define DN_NYT 8       // HDIM/128
#define GU_TG 8        // gateup supertile: t-group size
#define GU_NTG 9       // ceil(MAXT/GU_TG)
#define GU_NWG (GU_NTG * GU_NYT * GU_TG)   // 3168 = 8*396
#define DN_NWG (MAXT * DN_NYT)             // 568 = 8*71

typedef short bf16x8 __attribute__((ext_vector_type(8)));
typedef float f32x4 __attribute__((ext_vector_type(4)));
typedef unsigned short u16x8 __attribute__((ext_vector_type(8)));

static __device__ __forceinline__ unsigned short f2bf(float f) {
    union { float f; unsigned int i; } v; v.f = f;
    return (unsigned short)((v.i + 0x7fffu + ((v.i >> 16) & 1u)) >> 16);  // RNE
}

// async global->LDS, 16B/lane; LDS dest = wave-uniform base + lane*16
static __device__ __forceinline__ void gload16(const void* g, void* l) {
    __builtin_amdgcn_global_load_lds(
        (const __attribute__((address_space(1))) unsigned int*)g,
        (__attribute__((address_space(3))) unsigned int*)l, 16, 0, 0);
}

// ---------------------------------------------------------------------------
// 1) Gating: one wave per token, fp64 accumulate for stable top-2 ordering.
// ---------------------------------------------------------------------------
__global__ __launch_bounds__(256) void gating_kernel(
    const float* __restrict__ x, const float* __restrict__ Wgate,
    const float* __restrict__ bgate, float* __restrict__ logits_out,
    int* __restrict__ counts, int* __restrict__ topi, float* __restrict__ topv)
{
    int wave = (blockIdx.x << 2) + (threadIdx.x >> 6);
    int lane = threadIdx.x & 63;
    if (wave >= NTOK) return;
    const float* xr = x + (size_t)wave * HDIM;

    double acc[NEXP];
#pragma unroll
    for (int e = 0; e < NEXP; ++e) acc[e] = 0.0;

    for (int it = 0; it < HDIM / 64; ++it) {
        int h = lane + (it << 6);
        float xv = xr[h];
        const float* wr = Wgate + (size_t)h * NEXP;
#pragma unroll
        for (int e = 0; e < NEXP; ++e) acc[e] += (double)xv * (double)wr[e];
    }
#pragma unroll
    for (int e = 0; e < NEXP; ++e) {
        double v = acc[e];
        for (int off = 32; off; off >>= 1) v += __shfl_xor(v, off, 64);
        acc[e] = v + (double)bgate[e];
    }
    float lf[NEXP];
#pragma unroll
    for (int e = 0; e < NEXP; ++e) lf[e] = (float)acc[e];

    if (lane < NEXP) logits_out[(size_t)wave * NEXP + lane] = lf[lane];

    if (lane == 0) {
        int i1 = 0; float v1 = lf[0];
#pragma unroll
        for (int e = 1; e < NEXP; ++e) if (lf[e] > v1) { v1 = lf[e]; i1 = e; }
        int i2 = -1; float v2 = -3.0e38f;
#pragma unroll
        for (int e = 0; e < NEXP; ++e) {
            if (e == i1) continue;
            if (lf[e] > v2) { v2 = lf[e]; i2 = e; }
        }
        topi[wave * 2 + 0] = i1; topv[wave * 2 + 0] = v1;
        topi[wave * 2 + 1] = i2; topv[wave * 2 + 1] = v2;
        atomicAdd(&counts[i1], 1);
        atomicAdd(&counts[i2], 1);
    }
}

// ---------------------------------------------------------------------------
// 2) Offsets + device-built tile table (e, m0) per 128-row tile
// ---------------------------------------------------------------------------
__global__ void offsets_kernel(const int* __restrict__ counts,
                               int* __restrict__ offs, int* __restrict__ cursor,
                               int* __restrict__ ntile, int* __restrict__ te,
                               int* __restrict__ tm0)
{
    if (threadIdx.x == 0 && blockIdx.x == 0) {
        int s = 0;
        for (int e = 0; e < NEXP; ++e) { offs[e] = s; cursor[e] = s; s += counts[e]; }
        offs[NEXP] = s;
        int nt = 0;
        for (int e = 0; e < NEXP; ++e) {
            int c = counts[e], base = offs[e];
            for (int mt = 0; mt * 128 < c; ++mt) { te[nt] = e; tm0[nt] = base + mt * 128; ++nt; }
        }
        *ntile = nt;
    }
}

// ---------------------------------------------------------------------------
// 3) Scatter: pack selected token rows as bf16 into Xg[pos]; record weight+token
// ---------------------------------------------------------------------------
__global__ __launch_bounds__(256) void scatter_kernel(
    const float* __restrict__ x, const int* __restrict__ topi,
    const float* __restrict__ topv, int* __restrict__ cursor,
    float* __restrict__ row_w, int* __restrict__ tok_of,
    unsigned short* __restrict__ Xg)
{
    int p = (blockIdx.x << 2) + (threadIdx.x >> 6);
    int lane = threadIdx.x & 63;
    if (p >= NROWS) return;
    int n = p >> 1;
    int e = topi[p];
    float w = topv[p];
    int pos = 0;
    if (lane == 0) {
        pos = atomicAdd(&cursor[e], 1);
        row_w[pos] = w;
        tok_of[pos] = n;
    }
    pos = __shfl(pos, 0, 64);
    const float* xr = x + (size_t)n * HDIM;
    unsigned short* dst = Xg + (size_t)pos * HDIM;
#pragma unroll
    for (int it = 0; it < HDIM / 256; ++it) {
        int idx = (it * 64 + lane) * 4;
        float4 v = *reinterpret_cast<const float4*>(&xr[idx]);
        ushort4 o;
        o.x = f2bf(v.x); o.y = f2bf(v.y); o.z = f2bf(v.z); o.w = f2bf(v.w);
        *reinterpret_cast<ushort4*>(&dst[idx]) = o;
    }
}

// ---------------------------------------------------------------------------
// 4a) Gate+Up convert+transpose into interleaved W2[e][2I][H]:
//     row r2 = ((i>>4)<<5) + (kind<<4) + (i&15); kind 0=gate 1=up.
// ---------------------------------------------------------------------------
__global__ __launch_bounds__(256) void transpose_cvt_gu_kernel(
    const float* __restrict__ Wg, const float* __restrict__ Wu,
    unsigned short* __restrict__ W2)
{
    __shared__ unsigned short lds[64 * 66];
    const int kind = blockIdx.z;
    const int e = blockIdx.y;
    const float* s0 = (kind ? Wu : Wg) + (size_t)e * HDIM * IDIM;
    unsigned short* d0 = W2 + (size_t)e * 2 * IDIM * HDIM;
    const int TC = IDIM / 64;
    int tt = blockIdx.x;
    int tr = tt / TC, tc = tt % TC;
    int tid = threadIdx.x;
    {
        int r = tid >> 2, c0 = (tid & 3) << 4;
        const float* s = s0 + (size_t)(tr * 64 + r) * IDIM + tc * 64 + c0;
        float4 v0 = *reinterpret_cast<const float4*>(s);
        float4 v1 = *reinterpret_cast<const float4*>(s + 4);
        float4 v2 = *reinterpret_cast<const float4*>(s + 8);
        float4 v3 = *reinterpret_cast<const float4*>(s + 12);
        unsigned short* lr_ = &lds[r * 66 + c0];
        lr_[0]  = f2bf(v0.x); lr_[1]  = f2bf(v0.y); lr_[2]  = f2bf(v0.z); lr_[3]  = f2bf(v0.w);
        lr_[4]  = f2bf(v1.x); lr_[5]  = f2bf(v1.y); lr_[6]  = f2bf(v1.z); lr_[7]  = f2bf(v1.w);
        lr_[8]  = f2bf(v2.x); lr_[9]  = f2bf(v2.y); lr_[10] = f2bf(v2.z); lr_[11] = f2bf(v2.w);
        lr_[12] = f2bf(v3.x); lr_[13] = f2bf(v3.y); lr_[14] = f2bf(v3.z); lr_[15] = f2bf(v3.w);
    }
    __syncthreads();
    {
        int c = tid >> 2, q0 = (tid & 3) << 4;
        u16x8 o0, o1;
#pragma unroll
        for (int j = 0; j < 8; ++j) o0[j] = lds[(q0 + j) * 66 + c];
#pragma unroll
        for (int j = 0; j < 8; ++j) o1[j] = lds[(q0 + 8 + j) * 66 + c];
        int i = tc * 64 + c;                                  // src column
        int r2 = ((i >> 4) << 5) + (kind << 4) + (i & 15);    // interleaved row
        unsigned short* d = d0 + (size_t)r2 * HDIM + tr * 64 + q0;
        *reinterpret_cast<u16x8*>(d) = o0;
        *reinterpret_cast<u16x8*>(d + 8) = o1;
    }
}

// 4b) Plain transpose for Wd: fp32 [I][H] -> bf16 [H][I]
__global__ __launch_bounds__(256) void transpose_cvt_d_kernel(
    const float* __restrict__ Wd, unsigned short* __restrict__ Wdt)
{
    __shared__ unsigned short lds[64 * 66];
    const int e = blockIdx.y;
    const float* s0 = Wd + (size_t)e * IDIM * HDIM;
    unsigned short* d0 = Wdt + (size_t)e * HDIM * IDIM;
    const int TC = HDIM / 64;
    int tt = blockIdx.x;
    int tr = tt / TC, tc = tt % TC;
    int tid = threadIdx.x;
    {
        int r = tid >> 2, c0 = (tid & 3) << 4;
        const float* s = s0 + (size_t)(tr * 64 + r) * HDIM + tc * 64 + c0;
        float4 v0 = *reinterpret_cast<const float4*>(s);
        float4 v1 = *reinterpret_cast<const float4*>(s + 4);
        float4 v2 = *reinterpret_cast<const float4*>(s + 8);
        float4 v3 = *reinterpret_cast<const float4*>(s + 12);
        unsigned short* lr_ = &lds[r * 66 + c0];
        lr_[0]  = f2bf(v0.x); lr_[1]  = f2bf(v0.y); lr_[2]  = f2bf(v0.z); lr_[3]  = f2bf(v0.w);
        lr_[4]  = f2bf(v1.x); lr_[5]  = f2bf(v1.y); lr_[6]  = f2bf(v1.z); lr_[7]  = f2bf(v1.w);
        lr_[8]  = f2bf(v2.x); lr_[9]  = f2bf(v2.y); lr_[10] = f2bf(v2.z); lr_[11] = f2bf(v2.w);
        lr_[12] = f2bf(v3.x); lr_[13] = f2bf(v3.y); lr_[14] = f2bf(v3.z); lr_[15] = f2bf(v3.w);
    }
    __syncthreads();
    {
        int c = tid >> 2, q0 = (tid & 3) << 4;
        u16x8 o0, o1;
#pragma unroll
        for (int j = 0; j < 8; ++j) o0[j] = lds[(q0 + j) * 66 + c];
#pragma unroll
        for (int j = 0; j < 8; ++j) o1[j] = lds[(q0 + 8 + j) * 66 + c];
        unsigned short* d = d0 + (size_t)(tc * 64 + c) * IDIM + tr * 64 + q0;
        *reinterpret_cast<u16x8*>(d) = o0;
        *reinterpret_cast<u16x8*>(d + 8) = o1;
    }
}

// ---------------------------------------------------------------------------
// 5) Fused gate+up GEMM over bf16 W2 (interleaved 16g/16u columns):
//    128x128 tile, BK=64, 4 waves, all-gload16 staging with XOR-pre-swizzled
//    SOURCE (both sides, rule #21) + swizzled ds_read_b128 frag reads.
//    L2 supertile: tg of 8 tiles, ny outer / ti inner; bijective XCD chunk.
// ---------------------------------------------------------------------------
__global__ __launch_bounds__(256, 4) void gateup_kernel(
    const unsigned short* __restrict__ Xg,
    const unsigned short* __restrict__ W2,
    const int* __restrict__ offs,
    const int* __restrict__ ntile, const int* __restrict__ te,
    const int* __restrict__ tm0, unsigned short* __restrict__ hbuf)
{
    __shared__ unsigned short As[128 * 64];
    __shared__ unsigned short Bs[128 * 64];

    int bid = blockIdx.x;
    int xcd = bid & 7, rest = bid >> 3;
    int wg = xcd * (GU_NWG / 8) + rest;
    int tg = wg / (GU_NYT * GU_TG);
    int r2 = wg % (GU_NYT * GU_TG);
    int ny = r2 >> 3, ti = r2 & 7;
    int t = tg * GU_TG + ti;
    if (t >= *ntile) return;

    const int e = te[t];
    const int m0 = tm0[t];
    const int r1 = offs[e + 1];
    const int n0 = ny * 128;                 // i2 base

    const unsigned short* wb = W2 + (size_t)e * 2 * IDIM * HDIM;

    const int tid = threadIdx.x;
    const int lane = tid & 63, wv = tid >> 6;
    const int wr = (wv >> 1) * 64, wc = (wv & 1) * 64;
    const int lr = lane & 15, kq16 = lane >> 4;

    const int a_row8 = tid >> 3;            // 0..31
    const int a_c16 = tid & 7;

    f32x4 zero = {0.f, 0.f, 0.f, 0.f};
    f32x4 acc[4][4];
#pragma unroll
    for (int m = 0; m < 4; ++m)
#pragma unroll
        for (int n = 0; n < 4; ++n) acc[m][n] = zero;

    for (int k0 = 0; k0 < HDIM; k0 += 64) {
        __syncthreads();
#pragma unroll
        for (int ch = 0; ch < 4; ++ch) {
            int row = ch * 32 + a_row8;
            int c16s = a_c16 ^ (row & 7);                  // inverse swizzle on source
            gload16(&Xg[(size_t)(m0 + row) * HDIM + k0 + c16s * 8], &As[ch * 2048 + tid * 8]);
            gload16(&wb[(size_t)(n0 + row) * HDIM + k0 + c16s * 8], &Bs[ch * 2048 + tid * 8]);
        }
        __syncthreads();

#pragma unroll
        for (int ks = 0; ks < 2; ++ks) {
            bf16x8 af[4], bf[4];
#pragma unroll
            for (int m = 0; m < 4; ++m) {
                int row = wr + m * 16 + lr;
                int sw = (ks * 4 + kq16) ^ (row & 7);
                af[m] = *reinterpret_cast<const bf16x8*>(&As[row * 64 + sw * 8]);
            }
#pragma unroll
            for (int n = 0; n < 4; ++n) {
                int row = wc + n * 16 + lr;
                int sw = (ks * 4 + kq16) ^ (row & 7);
                bf[n] = *reinterpret_cast<const bf16x8*>(&Bs[row * 64 + sw * 8]);
            }
#pragma unroll
            for (int m = 0; m < 4; ++m)
#pragma unroll
                for (int n = 0; n < 4; ++n)
                    acc[m][n] = __builtin_amdgcn_mfma_f32_16x16x32_bf16(af[m], bf[n], acc[m][n], 0, 0, 0);
        }
    }

    // epilogue: frag parity n even = gate, n odd = up (same lane, same i)
    const int rr = (lane >> 4) * 4;
    const int iloc0 = ((wc >> 5) << 4) + lr;
    const int col0 = ny * 64 + iloc0;
#pragma unroll
    for (int m = 0; m < 4; ++m) {
#pragma unroll
        for (int j = 0; j < 4; ++j) {
            int grow = m0 + wr + m * 16 + rr + j;
            if (grow < r1) {
                unsigned short* hr = &hbuf[(size_t)grow * IDIM + col0];
                float g0 = acc[m][0][j], u0 = acc[m][1][j];
                float g1 = acc[m][2][j], u1 = acc[m][3][j];
                hr[0]  = f2bf(g0 / (1.0f + __expf(-g0)) * u0);
                hr[16] = f2bf(g1 / (1.0f + __expf(-g1)) * u1);
            }
        }
    }
}

// ---------------------------------------------------------------------------
// 6) Down GEMM + fused combine (atomicAdd into zeroed fp32 out).
//    Mapping: t outer / ny inner per XCD -> A panel (hbuf tile) reused 8x
//    from L2; Wdt (46 MB bf16) served via L3.
// ---------------------------------------------------------------------------
__global__ __launch_bounds__(256, 4) void down_kernel(
    const unsigned short* __restrict__ hbuf,
    const unsigned short* __restrict__ Wdt,   // [e][h][i] bf16
    const int* __restrict__ offs,
    const int* __restrict__ ntile, const int* __restrict__ te,
    const int* __restrict__ tm0,
    const float* __restrict__ row_w, const int* __restrict__ tok_of,
    float* __restrict__ out)
{
    __shared__ unsigned short As[128 * 64];
    __shared__ unsigned short Bs[128 * 64];

    int bid = blockIdx.x;                          // 568 = 8*71
    int xcd = bid & 7, rest = bid >> 3;
    int wg = xcd * (DN_NWG / 8) + rest;
    int t = wg >> 3;                               // A-tile (8 consecutive wgs share it)
    int ny = wg & 7;
    if (t >= *ntile) return;

    const int e = te[t];
    const int m0 = tm0[t];
    const int r1 = offs[e + 1];
    const int n0 = ny * 128;

    const unsigned short* wd = Wdt + (size_t)e * HDIM * IDIM;

    const int tid = threadIdx.x;
    const int lane = tid & 63, wv = tid >> 6;
    const int wr = (wv >> 1) * 64, wc = (wv & 1) * 64;
    const int lr = lane & 15, kq16 = lane >> 4;

    const int a_row8 = tid >> 3;
    const int a_c16 = tid & 7;

    f32x4 zero = {0.f, 0.f, 0.f, 0.f};
    f32x4 acc[4][4];
#pragma unroll
    for (int m = 0; m < 4; ++m)
#pragma unroll
        for (int n = 0; n < 4; ++n) acc[m][n] = zero;

    for (int k0 = 0; k0 < IDIM; k0 += 64) {
        __syncthreads();
#pragma unroll
        for (int ch = 0; ch < 4; ++ch) {
            int row = ch * 32 + a_row8;
            int c16s = a_c16 ^ (row & 7);
            gload16(&hbuf[(size_t)(m0 + row) * IDIM + k0 + c16s * 8], &As[ch * 2048 + tid * 8]);
            gload16(&wd[(size_t)(n0 + row) * IDIM + k0 + c16s * 8], &Bs[ch * 2048 + tid * 8]);
        }
        __syncthreads();

#pragma unroll
        for (int ks = 0; ks < 2; ++ks) {
            bf16x8 af[4], bf[4];
#pragma unroll
            for (int m = 0; m < 4; ++m) {
                int row = wr + m * 16 + lr;
                int sw = (ks * 4 + kq16) ^ (row & 7);
                af[m] = *reinterpret_cast<const bf16x8*>(&As[row * 64 + sw * 8]);
            }
#pragma unroll
            for (int n = 0; n < 4; ++n) {
                int row = wc + n * 16 + lr;
                int sw = (ks * 4 + kq16) ^ (row & 7);
                bf[n] = *reinterpret_cast<const bf16x8*>(&Bs[row * 64 + sw * 8]);
            }
#pragma unroll
            for (int m = 0; m < 4; ++m)
#pragma unroll
                for (int n = 0; n < 4; ++n)
                    acc[m][n] = __builtin_amdgcn_mfma_f32_16x16x32_bf16(af[m], bf[n], acc[m][n], 0, 0, 0);
        }
    }

    const int rr = (lane >> 4) * 4;
#pragma unroll
    for (int m = 0; m < 4; ++m) {
#pragma unroll
        for (int j = 0; j < 4; ++j) {
            int grow = m0 + wr + m * 16 + rr + j;
            if (grow < r1) {
                float w = row_w[grow];
                int tok = tok_of[grow];
                float* orow = out + (size_t)tok * HDIM + n0 + wc + lr;
#pragma unroll
                for (int n = 0; n < 4; ++n)
                    atomicAdd(&orow[n * 16], acc[m][n][j] * w);
            }
        }
    }
}

// ---------------------------------------------------------------------------
// ws layout (bytes):
//   [0,          17,039,360)   Xg bf16 [RPAD][HDIM]
//   [17,039,360, 63,897,600)   hbuf bf16 [RPAD][IDIM]
//   [63,897,600, 156,172,288)  W2 bf16 [E][2I][H]  (later aliased by Wdt [E][H][I])
//   [156,172,288, ...)         meta
// ---------------------------------------------------------------------------
extern "C" void kernel_launch(void* const* d_in, const int* in_sizes, int n_in,
                              void* d_out, int out_size, void* d_ws, size_t ws_size,
                              hipStream_t stream)
{
    const float* x     = (const float*)d_in[0];
    const float* Wgate = (const float*)d_in[1];
    const float* bgate = (const float*)d_in[2];
    const float* Wg    = (const float*)d_in[3];
    const float* Wu    = (const float*)d_in[4];
    const float* Wd    = (const float*)d_in[5];
    float* out = (float*)d_out;
    float* logits = out + (size_t)NTOK * HDIM;

    char* ws = (char*)d_ws;
    unsigned short* Xg   = (unsigned short*)ws;
    unsigned short* hbuf = (unsigned short*)(ws + 17039360);
    unsigned short* W2   = (unsigned short*)(ws + 63897600);   // also Wdt
    char* meta = ws + 156172288;
    int*   counts = (int*)(meta);
    int*   offs   = (int*)(meta + 64);
    int*   cursor = (int*)(meta + 128);
    int*   ntile  = (int*)(meta + 192);
    int*   te     = (int*)(meta + 256);     // 128 ints
    int*   tm0    = (int*)(meta + 768);     // 128 ints
    int*   topi   = (int*)(meta + 2048);    // NROWS ints
    float* topv   = (float*)(meta + 34816);
    float* row_w  = (float*)(meta + 67584);
    int*   tok_of = (int*)(meta + 100352);

    hipMemsetAsync(counts, 0, 32, stream);
    hipMemsetAsync(out, 0, (size_t)NTOK * HDIM * sizeof(float), stream);

    gating_kernel<<<NTOK / 4, 256, 0, stream>>>(x, Wgate, bgate, logits, counts, topi, topv);
    offsets_kernel<<<1, 64, 0, stream>>>(counts, offs, cursor, ntile, te, tm0);
    scatter_kernel<<<NROWS / 4, 256, 0, stream>>>(x, topi, topv, cursor, row_w, tok_of, Xg);

    // Wg,Wu fp32 [H][I] -> interleaved bf16 W2 [2I][H]
    transpose_cvt_gu_kernel<<<dim3((HDIM / 64) * (IDIM / 64), NEXP, 2), 256, 0, stream>>>(Wg, Wu, W2);

    gateup_kernel<<<GU_NWG, 256, 0, stream>>>(Xg, W2, offs, ntile, te, tm0, hbuf);

    // Wd fp32 [I][H] -> bf16 [H][I], aliased over W2 (dead after gateup)
    transpose_cvt_d_kernel<<<dim3((IDIM / 64) * (HDIM / 64), NEXP), 256, 0, stream>>>(Wd, W2);

    down_kernel<<<DN_NWG, 256, 0, stream>>>(hbuf, W2, offs, ntile, te, tm0, row_w, tok_of, out);
}